// Round 9
// baseline (93.395 us; speedup 1.0000x reference)
//
#include <hip/hip_runtime.h>
#include <math.h>

#define NTHREADS 256
#define CAP 4096                    // per-batch capacity of compacted arrays
#define NSBLK 544                   // blocks per batch (16x16 upper-tri x 4)

// ---- u = diff^2 LUT: float-bit indexed, nearest-midpoint, f32 entries.
#define LUTN 3072
#define OCT_LO (-16)
#define U_MIN 1.52587890625e-5f     // 2^-16
#define U_MAX 255.999f              // just under 2^8
#define IDX_BYTE_BIAS 56832u        // ((127-16)<<7) entries *4B, folded into base

typedef float v2f __attribute__((ext_vector_type(2)));

__device__ __forceinline__ float fsqrt(float x) {
#if __has_builtin(__builtin_amdgcn_sqrtf)
    return __builtin_amdgcn_sqrtf(x);
#else
    return sqrtf(x);
#endif
}
__device__ __forceinline__ float fmed3(float x, float lo, float hi) {
#if __has_builtin(__builtin_amdgcn_fmed3f)
    return __builtin_amdgcn_fmed3f(x, lo, hi);
#else
    return fminf(fmaxf(x, lo), hi);
#endif
}

__device__ __forceinline__ float sig4(float d) {
    const float e = expf(d);
    return 1.0f / (1.0f + e * 0.60653065971263342360f)
         + 1.0f / (1.0f + e * 0.36787944117144232160f)
         + 1.0f / (1.0f + e * 0.13533528323661269189f)
         + 1.0f / (1.0f + e * 0.01831563888873418029f);
}

__global__ __launch_bounds__(256) void lut_build_kernel(float* __restrict__ gLUT) {
    const int e = blockIdx.x * 256 + threadIdx.x;
    if (e < LUTN) {
        const int oct = e >> 7;
        const int k   = e & 127;
        const float base2 = exp2f((float)(oct + OCT_LO));
        const float umid = base2 * (1.0f + ((float)k + 0.5f) * 0.0078125f);
        gLUT[e] = sig4(fsqrt(umid));
    }
}

// ---- compact cm=1 atoms (stable order) into SoA arrays + sentinel padding ----
// C layout: 9 arrays of B*CAP floats: px,py,pz,tx,ty,tz,cut_nt,cut_other,ntf
__global__ __launch_bounds__(256) void compact_kernel(
    const float* __restrict__ pred, const float* __restrict__ tru,
    const int* __restrict__ dna, const int* __restrict__ rna,
    const int* __restrict__ cm,
    float* __restrict__ C, int* __restrict__ Mout, int n, int S /*=B*CAP*/)
{
    __shared__ int scan[256];
    const int b = blockIdx.x;
    const int tid = threadIdx.x;
    const size_t base = (size_t)b * n;
    const int npt = n / 256;            // elems per thread (16 for n=4096)

    int cnt = 0;
    unsigned int flags = 0;
    for (int k = 0; k < npt; ++k) {
        const int i = tid * npt + k;
        const int f = (cm[base + i] != 0) ? 1 : 0;
        flags |= (unsigned int)f << k;
        cnt += f;
    }
    scan[tid] = cnt;
    __syncthreads();
    for (int off = 1; off < 256; off <<= 1) {   // Hillis-Steele inclusive scan
        const int v = scan[tid];
        const int u = (tid >= off) ? scan[tid - off] : 0;
        __syncthreads();
        scan[tid] = v + u;
        __syncthreads();
    }
    const int M = scan[255];
    int pos = scan[tid] - cnt;          // exclusive prefix
    if (tid == 0) Mout[b] = M;

    float* cpx = C + 0 * S + b * CAP;  float* cpy = C + 1 * S + b * CAP;
    float* cpz = C + 2 * S + b * CAP;  float* ctx = C + 3 * S + b * CAP;
    float* cty = C + 4 * S + b * CAP;  float* ctz = C + 5 * S + b * CAP;
    float* ccn = C + 6 * S + b * CAP;  float* cco = C + 7 * S + b * CAP;
    float* cnt_f = C + 8 * S + b * CAP;

    for (int k = 0; k < npt; ++k) {
        if ((flags >> k) & 1u) {
            const int i = tid * npt + k;
            const float* p = pred + (base + i) * 3;
            const float* q = tru  + (base + i) * 3;
            const int nt = (dna[base + i] != 0) || (rna[base + i] != 0);
            cpx[pos] = p[0]; cpy[pos] = p[1]; cpz[pos] = p[2];
            ctx[pos] = q[0]; cty[pos] = q[1]; ctz[pos] = q[2];
            ccn[pos] = nt ? 900.0f : 225.0f;
            cco[pos] = 225.0f;
            cnt_f[pos] = nt ? 1.0f : 0.0f;
            ++pos;
        }
    }
    // sentinel padding [M, CAP): far coords, cut=0 -> contributes nothing
    for (int k = M + tid; k < CAP; k += 256) {
        cpx[k] = 1.0e9f; cpy[k] = 1.0e9f; cpz[k] = 1.0e9f;
        ctx[k] = 1.0e9f; cty[k] = 1.0e9f; ctz[k] = 1.0e9f;
        ccn[k] = 0.0f; cco[k] = 0.0f; cnt_f[k] = 0.0f;
    }
}

__device__ __forceinline__ void pair_tail(float sqp, float sqt, float cut2,
                                          const char* __restrict__ lutB,
                                          float& num, float& den) {
    const float r  = fsqrt(sqt * sqp);
    const float u0 = fmaf(-2.0f, r, sqt + sqp);
    const float u  = fmed3(u0, U_MIN, U_MAX);
    const unsigned int bits = __float_as_uint(u);
    const float s  = *(const float*)(lutB + ((bits >> 14) & ~3u));
    const float m  = (sqt < cut2) ? 1.0f : 0.0f;
    num = fmaf(m, s, num);
    den += m;
}

__global__ __launch_bounds__(NTHREADS) void lddt_tile_kernel(
    const float* __restrict__ C, const int* __restrict__ Mptr,
    const float* __restrict__ gLUT,
    float* __restrict__ pnum, float* __restrict__ pden, int S)
{
    __shared__ __align__(16) float sPX[256], sPY[256], sPZ[256];
    __shared__ __align__(16) float sTX[256], sTY[256], sTZ[256];
    __shared__ __align__(16) float sCut[2 * 256];
    __shared__ __align__(16) float sLUT[LUTN];
    __shared__ float wnum[4], wden[4];

    const int tid = threadIdx.x;

    // ---- decode block -> (bi, g, r, sc): super-tiles over upper triangle ----
    int s = blockIdx.x;
    const int bi = s / NSBLK;
    s -= bi * NSBLK;
    const int q = s >> 2;
    const int r = s & 3;
    const int W = 33;
    int g = (int)(((float)W - fsqrt((float)(W * W - 8 * q))) * 0.5f);
    while ((g + 1) * 16 - ((g + 1) * g) / 2 <= q) ++g;
    while (g * 16 - (g * (g - 1)) / 2 > q) --g;
    const int sc = g + (q - (g * 16 - (g * (g - 1)) / 2));
    const int ti = 4 * g + r;
    const int i0 = 64 * ti;
    const int J0 = 256 * sc;
    const bool has_diag = (sc == g);
    const int M = Mptr[bi];

    // blocks fully beyond the compacted count contribute nothing
    if (i0 >= M || J0 >= M) {
        if (tid == 0) { pnum[blockIdx.x] = 0.0f; pden[blockIdx.x] = 0.0f; }
        return;
    }

    const int bo = bi * CAP;
    const float* cpx = C + 0 * S + bo;  const float* cpy = C + 1 * S + bo;
    const float* cpz = C + 2 * S + bo;  const float* ctx = C + 3 * S + bo;
    const float* cty = C + 4 * S + bo;  const float* ctz = C + 5 * S + bo;
    const float* ccn = C + 6 * S + bo;  const float* cco = C + 7 * S + bo;
    const float* cntf = C + 8 * S + bo;

    // ---- LUT global->LDS ----
    {
        const float4* gl4 = (const float4*)gLUT;
        float4* sl4 = (float4*)sLUT;
        #pragma unroll
        for (int e = tid; e < LUTN / 4; e += NTHREADS) sl4[e] = gl4[e];
    }

    // ---- stage 256 compacted j's (coalesced SoA) ----
    {
        const int j = J0 + tid;
        sPX[tid] = cpx[j]; sPY[tid] = cpy[j]; sPZ[tid] = cpz[j];
        sTX[tid] = ctx[j]; sTY[tid] = cty[j]; sTZ[tid] = ctz[j];
        sCut[tid] = ccn[j]; sCut[256 + tid] = cco[j];
    }

    // ---- per-thread row: row = lane; wave w covers j-chunk [16w,16w+16) ----
    const int w = tid >> 6;
    const int l = tid & 63;
    const int i = i0 + l;
    const float pix = cpx[i], piy = cpy[i], piz = cpz[i];
    const float tix = ctx[i], tiy = cty[i], tiz = ctz[i];
    const bool nti = (cntf[i] != 0.0f);
    __syncthreads();

    const float* cutsel = nti ? &sCut[0] : &sCut[256];
    const char* lutB = (const char*)sLUT - IDX_BYTE_BIAS;
    const int kbase = 16 * w;

    const v2f px2 = {pix, pix}, py2 = {piy, piy}, pz2 = {piz, piz};
    const v2f tx2 = {tix, tix}, ty2 = {tiy, tiy}, tz2 = {tiz, tiz};

    float accn = 0.0f, accd = 0.0f;

    #pragma unroll
    for (int c = 0; c < 4; ++c) {
        const int tj = 4 * sc + c;
        if (tj < ti || 64 * tj >= M) continue;  // below diag or all-sentinel
        const bool diag = has_diag && (c == r);
        const int o = 64 * c;

        float num = 0.0f, den = 0.0f;
        #pragma unroll
        for (int qd = 0; qd < 4; ++qd) {
            const int jq = o + kbase + 4 * qd;
            const float4 PX = *(const float4*)&sPX[jq];
            const float4 PY = *(const float4*)&sPY[jq];
            const float4 PZ = *(const float4*)&sPZ[jq];
            const float4 TX = *(const float4*)&sTX[jq];
            const float4 TY = *(const float4*)&sTY[jq];
            const float4 TZ = *(const float4*)&sTZ[jq];
            const float4 CTC = *(const float4*)&cutsel[jq];

            v2f dx, dy, dz, sqpA, sqpB, sqtA, sqtB;

            dx = px2 - (v2f){PX.x, PX.y}; dy = py2 - (v2f){PY.x, PY.y}; dz = pz2 - (v2f){PZ.x, PZ.y};
            sqpA = dx * dx + dy * dy + dz * dz;
            dx = tx2 - (v2f){TX.x, TX.y}; dy = ty2 - (v2f){TY.x, TY.y}; dz = tz2 - (v2f){TZ.x, TZ.y};
            sqtA = dx * dx + dy * dy + dz * dz;

            dx = px2 - (v2f){PX.z, PX.w}; dy = py2 - (v2f){PY.z, PY.w}; dz = pz2 - (v2f){PZ.z, PZ.w};
            sqpB = dx * dx + dy * dy + dz * dz;
            dx = tx2 - (v2f){TX.z, TX.w}; dy = ty2 - (v2f){TY.z, TY.w}; dz = tz2 - (v2f){TZ.z, TZ.w};
            sqtB = dx * dx + dy * dy + dz * dz;

            pair_tail(sqpA.x, sqtA.x, CTC.x, lutB, num, den);
            pair_tail(sqpA.y, sqtA.y, CTC.y, lutB, num, den);
            pair_tail(sqpB.x, sqtB.x, CTC.z, lutB, num, den);
            pair_tail(sqpB.y, sqtB.y, CTC.w, lutB, num, den);
        }
        const float sc2 = diag ? 1.0f : 2.0f;   // symmetry weight
        accn = fmaf(sc2, num, accn);
        accd = fmaf(sc2, den, accd);
    }

    // remove self-pair: added iff real row (i<M) on diag tile with own j in chunk
    // (sentinel self-pair has cut2=0 -> never added)
    if (has_diag && ((l >> 4) == w) && i < M) {
        accn -= sLUT[0];
        accd -= 1.0f;
    }

    #pragma unroll
    for (int off = 32; off > 0; off >>= 1) {
        accn += __shfl_down(accn, off, 64);
        accd += __shfl_down(accd, off, 64);
    }
    if ((tid & 63) == 0) { wnum[w] = accn; wden[w] = accd; }
    __syncthreads();

    if (tid == 0) {
        pnum[blockIdx.x] = wnum[0] + wnum[1] + wnum[2] + wnum[3];
        pden[blockIdx.x] = wden[0] + wden[1] + wden[2] + wden[3];
    }
}

__global__ __launch_bounds__(256) void lddt_final_kernel(
    const float* __restrict__ pnum, const float* __restrict__ pden,
    float* __restrict__ out, int nsblk)
{
    __shared__ double sn0[4], sn1[4], sd0[4], sd1[4];
    double n0 = 0, n1 = 0, d0 = 0, d1 = 0;
    for (int s = threadIdx.x; s < 2 * nsblk; s += 256) {
        if (s < nsblk) { n0 += (double)pnum[s]; d0 += (double)pden[s]; }
        else           { n1 += (double)pnum[s]; d1 += (double)pden[s]; }
    }
    #pragma unroll
    for (int off = 32; off > 0; off >>= 1) {
        n0 += __shfl_down(n0, off, 64); d0 += __shfl_down(d0, off, 64);
        n1 += __shfl_down(n1, off, 64); d1 += __shfl_down(d1, off, 64);
    }
    const int w = threadIdx.x >> 6;
    if ((threadIdx.x & 63) == 0) { sn0[w] = n0; sn1[w] = n1; sd0[w] = d0; sd1[w] = d1; }
    __syncthreads();
    if (threadIdx.x == 0) {
        double N0 = sn0[0] + sn0[1] + sn0[2] + sn0[3];
        double N1 = sn1[0] + sn1[1] + sn1[2] + sn1[3];
        double D0 = sd0[0] + sd0[1] + sd0[2] + sd0[3];
        double D1 = sd1[0] + sd1[1] + sd1[2] + sd1[3];
        D0 = D0 > 1.0 ? D0 : 1.0;
        D1 = D1 > 1.0 ? D1 : 1.0;
        const double l0 = 0.25 * N0 / D0;
        const double l1 = 0.25 * N1 / D1;
        out[0] = (float)(1.0 - 0.5 * (l0 + l1));
    }
}

extern "C" void kernel_launch(void* const* d_in, const int* in_sizes, int n_in,
                              void* d_out, int out_size, void* d_ws, size_t ws_size,
                              hipStream_t stream) {
    const float* pred = (const float*)d_in[0];
    const float* tru  = (const float*)d_in[1];
    const int*   dna  = (const int*)d_in[2];
    const int*   rna  = (const int*)d_in[3];
    const int*   cm   = (const int*)d_in[4];
    float* out = (float*)d_out;

    const int B = 2;
    const int n = in_sizes[2] / B;        // 4096
    const int S = B * CAP;                // 8192

    // ws layout: [LUT 3072 f32 | C 9*S f32 | pnum B*NSBLK | pden B*NSBLK | M B ints]
    char* p = (char*)d_ws;
    float* gLUT = (float*)p;                 p += (size_t)LUTN * sizeof(float);
    float* C    = (float*)p;                 p += (size_t)9 * S * sizeof(float);
    float* pnum = (float*)p;                 p += (size_t)B * NSBLK * sizeof(float);
    float* pden = (float*)p;                 p += (size_t)B * NSBLK * sizeof(float);
    int*   Mout = (int*)p;

    hipLaunchKernelGGL(lut_build_kernel, dim3((LUTN + 255) / 256), dim3(256), 0, stream,
                       gLUT);
    hipLaunchKernelGGL(compact_kernel, dim3(B), dim3(256), 0, stream,
                       pred, tru, dna, rna, cm, C, Mout, n, S);
    hipLaunchKernelGGL(lddt_tile_kernel, dim3(B * NSBLK), dim3(NTHREADS), 0, stream,
                       C, Mout, gLUT, pnum, pden, S);
    hipLaunchKernelGGL(lddt_final_kernel, dim3(1), dim3(256), 0, stream,
                       pnum, pden, out, NSBLK);
}

// Round 10
// 76.398 us; speedup vs baseline: 1.2225x; 1.2225x over previous
//
#include <hip/hip_runtime.h>
#include <math.h>

#define NTHREADS 256
#define CAP 4096                    // per-batch capacity of compacted arrays
#define NSBLK 544                   // blocks per batch (16x16 upper-tri x 4)

// ---- u = diff^2 LUT: float-bit indexed, nearest-midpoint, f32 entries.
#define LUTN 3072
#define OCT_LO (-16)
#define U_MIN 1.52587890625e-5f     // 2^-16
#define U_MAX 255.999f              // just under 2^8
#define IDX_BYTE_BIAS 56832u        // ((127-16)<<7) entries *4B, folded into base

typedef float v2f __attribute__((ext_vector_type(2)));

__device__ __forceinline__ float fsqrt(float x) {
#if __has_builtin(__builtin_amdgcn_sqrtf)
    return __builtin_amdgcn_sqrtf(x);
#else
    return sqrtf(x);
#endif
}
__device__ __forceinline__ float fmed3(float x, float lo, float hi) {
#if __has_builtin(__builtin_amdgcn_fmed3f)
    return __builtin_amdgcn_fmed3f(x, lo, hi);
#else
    return fminf(fmaxf(x, lo), hi);
#endif
}

__device__ __forceinline__ float sig4(float d) {
    const float e = expf(d);
    return 1.0f / (1.0f + e * 0.60653065971263342360f)
         + 1.0f / (1.0f + e * 0.36787944117144232160f)
         + 1.0f / (1.0f + e * 0.13533528323661269189f)
         + 1.0f / (1.0f + e * 0.01831563888873418029f);
}

// ---- prep: build LUT + sentinel-fill C + zero compaction counters (one launch) ----
__global__ __launch_bounds__(256) void prep_kernel(
    float* __restrict__ gLUT, float* __restrict__ C, int* __restrict__ Mcnt, int S)
{
    const int gid = blockIdx.x * 256 + threadIdx.x;
    if (gid < LUTN) {
        const int oct = gid >> 7;
        const int k   = gid & 127;
        const float base2 = exp2f((float)(oct + OCT_LO));
        const float umid = base2 * (1.0f + ((float)k + 0.5f) * 0.0078125f);
        gLUT[gid] = sig4(fsqrt(umid));
    }
    if (gid < 2) Mcnt[gid] = 0;
    // sentinel fill: coords (arrays 0-5) = 1e9 (safe: (3e18)^2 ~ 9e36 < FLT_MAX),
    // cuts + ntf (arrays 6-8) = 0 -> sentinel pairs never pass the mask
    const int total = 9 * S;
    const int stride = gridDim.x * 256;
    for (int idx = gid; idx < total; idx += stride)
        C[idx] = (idx < 6 * S) ? 1.0e9f : 0.0f;
}

// ---- parallel compaction: 1 atom/thread, 16 chunks/batch, atomic range reserve.
// Chunk order is nondeterministic -> atom order permuted; pair sums are
// order-invariant so the result is unchanged (fp-association noise only).
__global__ __launch_bounds__(256) void compact_kernel(
    const float* __restrict__ pred, const float* __restrict__ tru,
    const int* __restrict__ dna, const int* __restrict__ rna,
    const int* __restrict__ cm,
    float* __restrict__ C, int* __restrict__ Mcnt, int n, int S)
{
    __shared__ int scan[256];
    __shared__ int sbase;
    const int chunks = n / 256;            // 16
    const int b = blockIdx.x / chunks;
    const int chunk = blockIdx.x % chunks;
    const int tid = threadIdx.x;
    const size_t gi = (size_t)b * n + chunk * 256 + tid;

    const int f = (cm[gi] != 0) ? 1 : 0;
    scan[tid] = f;
    __syncthreads();
    #pragma unroll
    for (int off = 1; off < 256; off <<= 1) {   // Hillis-Steele inclusive scan
        const int v = scan[tid];
        const int u = (tid >= off) ? scan[tid - off] : 0;
        __syncthreads();
        scan[tid] = v + u;
        __syncthreads();
    }
    if (tid == 255) sbase = atomicAdd(&Mcnt[b], scan[255]);
    __syncthreads();

    if (f) {
        const int pos = sbase + scan[tid] - 1;   // consecutive -> coalesced writes
        const float* p = pred + gi * 3;
        const float* q = tru  + gi * 3;
        const int nt = (dna[gi] != 0) || (rna[gi] != 0);
        const int bo = b * CAP;
        C[0 * S + bo + pos] = p[0];  C[1 * S + bo + pos] = p[1];
        C[2 * S + bo + pos] = p[2];  C[3 * S + bo + pos] = q[0];
        C[4 * S + bo + pos] = q[1];  C[5 * S + bo + pos] = q[2];
        C[6 * S + bo + pos] = nt ? 900.0f : 225.0f;
        C[7 * S + bo + pos] = 225.0f;
        C[8 * S + bo + pos] = nt ? 1.0f : 0.0f;
    }
}

__device__ __forceinline__ void pair_tail(float sqp, float sqt, float cut2,
                                          const char* __restrict__ lutB,
                                          float& num, float& den) {
    const float r  = fsqrt(sqt * sqp);
    const float u0 = fmaf(-2.0f, r, sqt + sqp);
    const float u  = fmed3(u0, U_MIN, U_MAX);
    const unsigned int bits = __float_as_uint(u);
    const float s  = *(const float*)(lutB + ((bits >> 14) & ~3u));
    const float m  = (sqt < cut2) ? 1.0f : 0.0f;
    num = fmaf(m, s, num);
    den += m;
}

__global__ __launch_bounds__(NTHREADS) void lddt_tile_kernel(
    const float* __restrict__ C, const int* __restrict__ Mptr,
    const float* __restrict__ gLUT,
    float* __restrict__ pnum, float* __restrict__ pden, int S)
{
    __shared__ __align__(16) float sPX[256], sPY[256], sPZ[256];
    __shared__ __align__(16) float sTX[256], sTY[256], sTZ[256];
    __shared__ __align__(16) float sCut[2 * 256];
    __shared__ __align__(16) float sLUT[LUTN];
    __shared__ float wnum[4], wden[4];

    const int tid = threadIdx.x;

    int s = blockIdx.x;
    const int bi = s / NSBLK;
    s -= bi * NSBLK;
    const int q = s >> 2;
    const int r = s & 3;
    const int W = 33;
    int g = (int)(((float)W - fsqrt((float)(W * W - 8 * q))) * 0.5f);
    while ((g + 1) * 16 - ((g + 1) * g) / 2 <= q) ++g;
    while (g * 16 - (g * (g - 1)) / 2 > q) --g;
    const int sc = g + (q - (g * 16 - (g * (g - 1)) / 2));
    const int ti = 4 * g + r;
    const int i0 = 64 * ti;
    const int J0 = 256 * sc;
    const bool has_diag = (sc == g);
    const int M = Mptr[bi];

    if (i0 >= M || J0 >= M) {
        if (tid == 0) { pnum[blockIdx.x] = 0.0f; pden[blockIdx.x] = 0.0f; }
        return;
    }

    const int bo = bi * CAP;
    const float* cpx = C + 0 * S + bo;  const float* cpy = C + 1 * S + bo;
    const float* cpz = C + 2 * S + bo;  const float* ctx = C + 3 * S + bo;
    const float* cty = C + 4 * S + bo;  const float* ctz = C + 5 * S + bo;
    const float* ccn = C + 6 * S + bo;  const float* cco = C + 7 * S + bo;
    const float* cntf = C + 8 * S + bo;

    {
        const float4* gl4 = (const float4*)gLUT;
        float4* sl4 = (float4*)sLUT;
        #pragma unroll
        for (int e = tid; e < LUTN / 4; e += NTHREADS) sl4[e] = gl4[e];
    }
    {
        const int j = J0 + tid;
        sPX[tid] = cpx[j]; sPY[tid] = cpy[j]; sPZ[tid] = cpz[j];
        sTX[tid] = ctx[j]; sTY[tid] = cty[j]; sTZ[tid] = ctz[j];
        sCut[tid] = ccn[j]; sCut[256 + tid] = cco[j];
    }

    const int w = tid >> 6;
    const int l = tid & 63;
    const int i = i0 + l;
    const float pix = cpx[i], piy = cpy[i], piz = cpz[i];
    const float tix = ctx[i], tiy = cty[i], tiz = ctz[i];
    const bool nti = (cntf[i] != 0.0f);
    __syncthreads();

    const float* cutsel = nti ? &sCut[0] : &sCut[256];
    const char* lutB = (const char*)sLUT - IDX_BYTE_BIAS;
    const int kbase = 16 * w;

    const v2f px2 = {pix, pix}, py2 = {piy, piy}, pz2 = {piz, piz};
    const v2f tx2 = {tix, tix}, ty2 = {tiy, tiy}, tz2 = {tiz, tiz};

    float accn = 0.0f, accd = 0.0f;

    #pragma unroll
    for (int c = 0; c < 4; ++c) {
        const int tj = 4 * sc + c;
        if (tj < ti || 64 * tj >= M) continue;
        const bool diag = has_diag && (c == r);
        const int o = 64 * c;

        float num = 0.0f, den = 0.0f;
        #pragma unroll
        for (int qd = 0; qd < 4; ++qd) {
            const int jq = o + kbase + 4 * qd;
            const float4 PX = *(const float4*)&sPX[jq];
            const float4 PY = *(const float4*)&sPY[jq];
            const float4 PZ = *(const float4*)&sPZ[jq];
            const float4 TX = *(const float4*)&sTX[jq];
            const float4 TY = *(const float4*)&sTY[jq];
            const float4 TZ = *(const float4*)&sTZ[jq];
            const float4 CTC = *(const float4*)&cutsel[jq];

            v2f dx, dy, dz, sqpA, sqpB, sqtA, sqtB;

            dx = px2 - (v2f){PX.x, PX.y}; dy = py2 - (v2f){PY.x, PY.y}; dz = pz2 - (v2f){PZ.x, PZ.y};
            sqpA = dx * dx + dy * dy + dz * dz;
            dx = tx2 - (v2f){TX.x, TX.y}; dy = ty2 - (v2f){TY.x, TY.y}; dz = tz2 - (v2f){TZ.x, TZ.y};
            sqtA = dx * dx + dy * dy + dz * dz;

            dx = px2 - (v2f){PX.z, PX.w}; dy = py2 - (v2f){PY.z, PY.w}; dz = pz2 - (v2f){PZ.z, PZ.w};
            sqpB = dx * dx + dy * dy + dz * dz;
            dx = tx2 - (v2f){TX.z, TX.w}; dy = ty2 - (v2f){TY.z, TY.w}; dz = tz2 - (v2f){TZ.z, TZ.w};
            sqtB = dx * dx + dy * dy + dz * dz;

            pair_tail(sqpA.x, sqtA.x, CTC.x, lutB, num, den);
            pair_tail(sqpA.y, sqtA.y, CTC.y, lutB, num, den);
            pair_tail(sqpB.x, sqtB.x, CTC.z, lutB, num, den);
            pair_tail(sqpB.y, sqtB.y, CTC.w, lutB, num, den);
        }
        const float sc2 = diag ? 1.0f : 2.0f;   // symmetry weight
        accn = fmaf(sc2, num, accn);
        accd = fmaf(sc2, den, accd);
    }

    // remove self-pair (added once on diag tile iff lane's chunk holds j=l and
    // the row is a real atom; sentinel self-pair has cut2=0 -> never added)
    if (has_diag && ((l >> 4) == w) && i < M) {
        accn -= sLUT[0];
        accd -= 1.0f;
    }

    #pragma unroll
    for (int off = 32; off > 0; off >>= 1) {
        accn += __shfl_down(accn, off, 64);
        accd += __shfl_down(accd, off, 64);
    }
    if ((tid & 63) == 0) { wnum[w] = accn; wden[w] = accd; }
    __syncthreads();

    if (tid == 0) {
        pnum[blockIdx.x] = wnum[0] + wnum[1] + wnum[2] + wnum[3];
        pden[blockIdx.x] = wden[0] + wden[1] + wden[2] + wden[3];
    }
}

__global__ __launch_bounds__(256) void lddt_final_kernel(
    const float* __restrict__ pnum, const float* __restrict__ pden,
    float* __restrict__ out, int nsblk)
{
    __shared__ double sn0[4], sn1[4], sd0[4], sd1[4];
    double n0 = 0, n1 = 0, d0 = 0, d1 = 0;
    for (int s = threadIdx.x; s < 2 * nsblk; s += 256) {
        if (s < nsblk) { n0 += (double)pnum[s]; d0 += (double)pden[s]; }
        else           { n1 += (double)pnum[s]; d1 += (double)pden[s]; }
    }
    #pragma unroll
    for (int off = 32; off > 0; off >>= 1) {
        n0 += __shfl_down(n0, off, 64); d0 += __shfl_down(d0, off, 64);
        n1 += __shfl_down(n1, off, 64); d1 += __shfl_down(d1, off, 64);
    }
    const int w = threadIdx.x >> 6;
    if ((threadIdx.x & 63) == 0) { sn0[w] = n0; sn1[w] = n1; sd0[w] = d0; sd1[w] = d1; }
    __syncthreads();
    if (threadIdx.x == 0) {
        double N0 = sn0[0] + sn0[1] + sn0[2] + sn0[3];
        double N1 = sn1[0] + sn1[1] + sn1[2] + sn1[3];
        double D0 = sd0[0] + sd0[1] + sd0[2] + sd0[3];
        double D1 = sd1[0] + sd1[1] + sd1[2] + sd1[3];
        D0 = D0 > 1.0 ? D0 : 1.0;
        D1 = D1 > 1.0 ? D1 : 1.0;
        const double l0 = 0.25 * N0 / D0;
        const double l1 = 0.25 * N1 / D1;
        out[0] = (float)(1.0 - 0.5 * (l0 + l1));
    }
}

extern "C" void kernel_launch(void* const* d_in, const int* in_sizes, int n_in,
                              void* d_out, int out_size, void* d_ws, size_t ws_size,
                              hipStream_t stream) {
    const float* pred = (const float*)d_in[0];
    const float* tru  = (const float*)d_in[1];
    const int*   dna  = (const int*)d_in[2];
    const int*   rna  = (const int*)d_in[3];
    const int*   cm   = (const int*)d_in[4];
    float* out = (float*)d_out;

    const int B = 2;
    const int n = in_sizes[2] / B;        // 4096
    const int S = B * CAP;                // 8192

    // ws layout: [LUT 3072 f32 | C 9*S f32 | pnum B*NSBLK | pden B*NSBLK | Mcnt B]
    char* p = (char*)d_ws;
    float* gLUT = (float*)p;                 p += (size_t)LUTN * sizeof(float);
    float* C    = (float*)p;                 p += (size_t)9 * S * sizeof(float);
    float* pnum = (float*)p;                 p += (size_t)B * NSBLK * sizeof(float);
    float* pden = (float*)p;                 p += (size_t)B * NSBLK * sizeof(float);
    int*   Mcnt = (int*)p;

    hipLaunchKernelGGL(prep_kernel, dim3(288), dim3(256), 0, stream,
                       gLUT, C, Mcnt, S);
    hipLaunchKernelGGL(compact_kernel, dim3(B * (n / 256)), dim3(256), 0, stream,
                       pred, tru, dna, rna, cm, C, Mcnt, n, S);
    hipLaunchKernelGGL(lddt_tile_kernel, dim3(B * NSBLK), dim3(NTHREADS), 0, stream,
                       C, Mcnt, gLUT, pnum, pden, S);
    hipLaunchKernelGGL(lddt_final_kernel, dim3(1), dim3(256), 0, stream,
                       pnum, pden, out, NSBLK);
}